// Round 5
// baseline (106.980 us; speedup 1.0000x reference)
//
#include <hip/hip_runtime.h>

// Quantum circuit sim: 12 wires, DIM=4096, 3 layers, batch=512, fp32.
// R5 = R4 body + DIAGNOSTIC double-pass: the identical circuit+measurement
// runs twice (pass 2 consumes pass 1's final register state and stores its
// reduction to d_ws, so it cannot be dead-code-eliminated and does not
// affect d_out). This lifts the dispatch above the 41-us harness fills so
// rocprof top-5 finally shows OUR counters (VALUBusy is the decisive one:
// >55% => instruction bloat; ~20% => structural stall).
//
// R4 structure recap:
//  - LDS layout f(i) = 18*(i>>4) + (i&15): per-phase addressing is one base
//    VGPR + immediate offsets; conflict-minimal in every phase; C-phase pairs
//    are 16-B aligned for b128.
//  - float2 packed math -> v_pk_fma_f32.
//  - Double-buffered LDS, 9 barriers per pass.
//  - CNOT chain folded to Gray map perm(i)=i^(i>>1) in gather addresses;
//    final perm folded into measurement weights via inverse-Gray.

namespace {

constexpr int N_WIRES  = 12;
constexpr int DIM      = 1 << N_WIRES;        // 4096
constexpr int THREADS  = 256;
constexpr int PER      = 16;                  // amps per thread
constexpr int NGATES   = 36;
constexpr int PADC     = 4606;                // max f(i) = 288*15+18*15+15 = 4605

__device__ __forceinline__ float2 axpy(float s, float2 v, float2 a) {
    return make_float2(s * v.x + a.x, s * v.y + a.y);  // contracts to pk_fma
}
__device__ __forceinline__ float2 scal(float s, float2 v) {
    return make_float2(s * v.x, s * v.y);
}
__device__ __forceinline__ float2 Jrot(float2 v) { return make_float2(-v.y, v.x); }

// 4 in-register gates; gate gg pairs k-bit (3-gg). Umat[g] = {u00,u01,u10,u11}.
__device__ __forceinline__ void apply4(float2 amp[PER],
                                       const float2 (*Um)[4], int gbase)
{
    #pragma unroll
    for (int gg = 0; gg < 4; ++gg) {
        const float2 u00 = Um[gbase + gg][0];
        const float2 u01 = Um[gbase + gg][1];
        const float2 u10 = Um[gbase + gg][2];
        const float2 u11 = Um[gbase + gg][3];
        const int st = 8 >> gg;
        #pragma unroll
        for (int k0 = 0; k0 < PER; ++k0) {
            if (k0 & st) continue;              // static under full unroll
            const int k1 = k0 | st;
            const float2 p = amp[k0], q = amp[k1];
            const float2 jp = Jrot(p), jq = Jrot(q);
            float2 np = scal(u00.x, p);
            np = axpy(u00.y, jp, np);
            np = axpy(u01.x, q,  np);
            np = axpy(u01.y, jq, np);
            float2 nq = scal(u10.x, p);
            nq = axpy(u10.y, jp, nq);
            nq = axpy(u11.x, q,  nq);
            nq = axpy(u11.y, jq, nq);
            amp[k0] = np;
            amp[k1] = nq;
        }
    }
}

__global__ __launch_bounds__(THREADS, 2)
void qcirc_kernel(const float* __restrict__ state,
                  const float* __restrict__ weights,
                  const float* __restrict__ head_w,
                  const float* __restrict__ head_b,
                  float* __restrict__ out,
                  float* __restrict__ dbg)
{
    __shared__ __align__(16) float2 buf[2][PADC];
    __shared__ __align__(16) float2 Umat[NGATES][4];
    __shared__ float redbuf[THREADS / 64];

    const int t = threadIdx.x;                 // 8 bits
    const int b = blockIdx.x;

    // ---- 36 gate matrices. U = RZ(c)RY(b)RX(a); SU(2):
    // U = [[u00, -conj(u10)], [u10, conj(u00)]].
    if (t < NGATES) {
        const float* wp = weights + t * 3;
        float ha = 0.5f * wp[0], hb = 0.5f * wp[1], hc = 0.5f * wp[2];
        float ca = cosf(ha), sa = sinf(ha);
        float cb = cosf(hb), sb = sinf(hb);
        float ecr = cosf(hc), eci = -sinf(hc);   // e^{-i c/2}
        float t0 = cb * ca, t1 = sb * sa, t2 = sb * ca, t3 = cb * sa;
        float u00r =  ecr * t0 - eci * t1;
        float u00i =  ecr * t1 + eci * t0;
        float u10r =  ecr * t2 - eci * t3;
        float u10i = -ecr * t3 - eci * t2;
        Umat[t][0] = make_float2( u00r,  u00i);   // u00
        Umat[t][1] = make_float2(-u10r,  u10i);   // u01 = -conj(u10)
        Umat[t][2] = make_float2( u10r,  u10i);   // u10
        Umat[t][3] = make_float2( u00r, -u00i);   // u11 = conj(u00)
    }

    // ---- Phase bases (f(i) = 18*(i>>4) + (i&15), float2 units).
    const int T  = t >> 4, u = t & 15;
    const int bA = 18 * T + u;                  // A write: i=(k<<8)|t, +288k
    const int bB = 288 * T + u;                 // B r/w:  i=(T<<8)|(k<<4)|u, +18k
    const int bC = 18 * t;                      // C r/w:  i=(t<<4)|k, +k (b128 pairs)
    const int tb  = t ^ (t >> 1);               // Gray(t), 8-bit
    const int tbx = tb ^ 128;
    const int pb0 = 18 * (tb  >> 4) + (tb  & 15);  // gather base, k even
    const int pb1 = 18 * (tbx >> 4) + (tbx & 15);  // gather base, k odd

    // ---- Measurement constants (uniform per thread across both passes).
    float hw[N_WIRES];
    #pragma unroll
    for (int w = 0; w < N_WIRES; ++w) hw[w] = head_w[w];
    int it = t ^ (t >> 1); it ^= it >> 2; it ^= it >> 4;   // invGray8(t)
    float chi = 0.f;
    #pragma unroll
    for (int w = 0; w < 8; ++w)
        chi += ((it >> (7 - w)) & 1) ? -hw[w] : hw[w];
    const int parfill = (__popc(t) & 1) ? 0xF : 0;

    // ---- Initial load, A-layout: amp[k] = state[(k<<8)|t] (coalesced).
    float2 amp[PER];
    {
        const float* sp = state + (size_t)b * DIM;
        #pragma unroll
        for (int k = 0; k < PER; ++k)
            amp[k] = make_float2(sp[(k << 8) | t], 0.f);
    }
    __syncthreads();   // Umat ready

    #pragma unroll 1   // keep ONE copy of the circuit body (I-cache)
    for (int pass = 0; pass < 2; ++pass) {
        #pragma unroll
        for (int l = 0; l < 3; ++l) {
            const int gb = l * 12;
            if (l > 0) {
                // Gather through CNOT perm into A-layout:
                // new[(k<<8)|t] = old[j], j = (gray4(k)<<8)|(gray8(t)^((k&1)<<7)).
                const float2* src = buf[(3 * l - 1) & 1];
                #pragma unroll
                for (int k = 0; k < PER; ++k) {
                    const int g = k ^ (k >> 1);             // gray4(k), static
                    amp[k] = src[((k & 1) ? pb1 : pb0) + 288 * g];
                }
            }

            // Group A: wires 0-3 (i bits 11-8 = k)
            apply4(amp, Umat, gb + 0);
            {
                float2* w = &buf[(3 * l) & 1][bA];
                #pragma unroll
                for (int k = 0; k < PER; ++k) w[288 * k] = amp[k];
            }
            __syncthreads();
            {
                const float2* r = &buf[(3 * l) & 1][bB];
                #pragma unroll
                for (int k = 0; k < PER; ++k) amp[k] = r[18 * k];
            }

            // Group B: wires 4-7 (i bits 7-4 = k)
            apply4(amp, Umat, gb + 4);
            {
                float2* w = &buf[(3 * l + 1) & 1][bB];
                #pragma unroll
                for (int k = 0; k < PER; ++k) w[18 * k] = amp[k];
            }
            __syncthreads();
            {
                const float4* r = reinterpret_cast<const float4*>(&buf[(3 * l + 1) & 1][bC]);
                #pragma unroll
                for (int k = 0; k < PER / 2; ++k) {
                    float4 v = r[k];
                    amp[2 * k]     = make_float2(v.x, v.y);
                    amp[2 * k + 1] = make_float2(v.z, v.w);
                }
            }

            // Group C: wires 8-11 (i bits 3-0 = k)
            apply4(amp, Umat, gb + 8);
            if (l < 2) {
                float4* w = reinterpret_cast<float4*>(&buf[(3 * l + 2) & 1][bC]);
                #pragma unroll
                for (int k = 0; k < PER / 2; ++k)
                    w[k] = make_float4(amp[2 * k].x, amp[2 * k].y,
                                       amp[2 * k + 1].x, amp[2 * k + 1].y);
                __syncthreads();
            }
        }

        // ---- Measurement. Regs hold pre-perm state at j=(t<<4)|k; logical
        // m = invGray12(j): m[11:4]=invGray8(t), m[3:0]=invGray4(k)^(par(t)*0xF).
        float acc = 0.f;
        #pragma unroll
        for (int k = 0; k < PER; ++k) {
            int ml = (k ^ (k >> 1)); ml ^= ml >> 2; ml ^= parfill;  // m[3:0]
            float c = chi;
            c += ((ml >> 3) & 1) ? -hw[8]  : hw[8];
            c += ((ml >> 2) & 1) ? -hw[9]  : hw[9];
            c += ((ml >> 1) & 1) ? -hw[10] : hw[10];
            c += ( ml       & 1) ? -hw[11] : hw[11];
            float p = amp[k].x * amp[k].x + amp[k].y * amp[k].y;
            acc += p * c;
        }

        #pragma unroll
        for (int off = 32; off > 0; off >>= 1)
            acc += __shfl_down(acc, off, 64);
        if ((t & 63) == 0) redbuf[t >> 6] = acc;
        __syncthreads();
        if (t == 0) {
            float s = 0.f;
            #pragma unroll
            for (int q = 0; q < THREADS / 64; ++q) s += redbuf[q];
            s += head_b[0];
            if (pass == 0) out[b] = s;      // real result
            else           dbg[b] = s;      // diagnostic pass -> scratch
        }
        // pass 2 reuses the final register state as its input (bounded:
        // unitary evolution preserves norm; values stay O(1), no NaN risk).
        // Hazard check: pass-2's first LDS write targets buf[0]; the last
        // pass-1 reads of buf[0] (l=2 B-read) are ordered before the l=2
        // mid-phase barrier, and the measurement barrier above orders redbuf.
    }
}

} // namespace

extern "C" void kernel_launch(void* const* d_in, const int* in_sizes, int n_in,
                              void* d_out, int out_size, void* d_ws, size_t ws_size,
                              hipStream_t stream)
{
    const float* state   = (const float*)d_in[0];  // (B, 4096) fp32
    const float* weights = (const float*)d_in[1];  // (3, 12, 3) fp32
    const float* head_w  = (const float*)d_in[2];  // (1, 12) fp32
    const float* head_b  = (const float*)d_in[3];  // (1,) fp32
    float* out = (float*)d_out;                    // (B,) fp32
    float* dbg = (float*)d_ws;                     // diagnostic-pass sink

    const int batch = in_sizes[0] / DIM;           // 512
    qcirc_kernel<<<batch, THREADS, 0, stream>>>(state, weights, head_w, head_b,
                                                out, dbg);
}

// Round 6
// 91.492 us; speedup vs baseline: 1.1693x; 1.1693x over previous
//
#include <hip/hip_runtime.h>

// Quantum circuit sim: 12 wires, DIM=4096, 3 layers, batch=512, fp32.
// R6 = R5 structure + inline-asm packed complex math (v_pk_fma_f32 / 
// v_pk_mul_f32 with op_sel/neg_lo modifiers). R5's counters showed
// VALUBusy=65% with ~11K VALU inst/thread/pass vs a 4.6K scalar-FMA hand
// count -> compiler bloat. The asm core pins each complex FMA at exactly
// 2 VOP3P instructions: 8 per gate-pair, 2304 per thread per pass.
// Double-pass diagnostic retained (pass 2 -> d_ws) for counter visibility.
//
// Structure recap:
//  - LDS layout f(i) = 18*(i>>4) + (i&15): per-phase addressing = one base
//    VGPR + immediate offsets; conflict-minimal; C-phase 16-B aligned b128.
//  - Double-buffered LDS, 9 barriers per pass.
//  - CNOT chain folded to Gray map perm(i)=i^(i>>1) in gather addresses;
//    final perm folded into measurement weights via inverse-Gray.

namespace {

typedef float v2f __attribute__((ext_vector_type(2)));

constexpr int N_WIRES  = 12;
constexpr int DIM      = 1 << N_WIRES;        // 4096
constexpr int THREADS  = 256;
constexpr int PER      = 16;                  // amps per thread
constexpr int NGATES   = 36;
constexpr int PADC     = 4606;                // max f(i) = 288*15+18*15+15 = 4605

// ---- Packed complex helpers. v2f = (re, im) in a VGPR pair.
// d = u * p  (complex product):
//   inst1: d.lo = p.re*u.re            d.hi = p.im*u.re
//   inst2: d.lo += p.im*(-u.im)        d.hi += p.re*u.im
__device__ __forceinline__ v2f cmul(v2f u, v2f p) {
    v2f d;
    asm("v_pk_mul_f32 %0, %1, %2 op_sel_hi:[1,0]"
        : "=v"(d) : "v"(p), "v"(u));
    asm("v_pk_fma_f32 %0, %1, %2, %0 op_sel:[1,1,0] op_sel_hi:[0,1,1] neg_lo:[0,1,0]"
        : "+v"(d) : "v"(p), "v"(u));
    return d;
}
// d += u * p
__device__ __forceinline__ void cfma(v2f& d, v2f u, v2f p) {
    asm("v_pk_fma_f32 %0, %1, %2, %0 op_sel_hi:[1,0,1]"
        : "+v"(d) : "v"(p), "v"(u));
    asm("v_pk_fma_f32 %0, %1, %2, %0 op_sel:[1,1,0] op_sel_hi:[0,1,1] neg_lo:[0,1,0]"
        : "+v"(d) : "v"(p), "v"(u));
}

// 4 in-register gates; gate gg pairs k-bit (3-gg). Um[g] = {u00,u01,u10,u11}.
__device__ __forceinline__ void apply4(v2f amp[PER], const v2f (*Um)[4], int gbase)
{
    #pragma unroll
    for (int gg = 0; gg < 4; ++gg) {
        const v2f u00 = Um[gbase + gg][0];
        const v2f u01 = Um[gbase + gg][1];
        const v2f u10 = Um[gbase + gg][2];
        const v2f u11 = Um[gbase + gg][3];
        const int st = 8 >> gg;
        #pragma unroll
        for (int k0 = 0; k0 < PER; ++k0) {
            if (k0 & st) continue;              // static under full unroll
            const int k1 = k0 | st;
            const v2f p = amp[k0], q = amp[k1];
            v2f np = cmul(u00, p); cfma(np, u01, q);
            v2f nq = cmul(u10, p); cfma(nq, u11, q);
            amp[k0] = np;
            amp[k1] = nq;
        }
    }
}

__global__ __launch_bounds__(THREADS, 2)
void qcirc_kernel(const float* __restrict__ state,
                  const float* __restrict__ weights,
                  const float* __restrict__ head_w,
                  const float* __restrict__ head_b,
                  float* __restrict__ out,
                  float* __restrict__ dbg)
{
    __shared__ __align__(16) v2f buf[2][PADC];
    __shared__ __align__(16) v2f Umat[NGATES][4];
    __shared__ float redbuf[THREADS / 64];

    const int t = threadIdx.x;                 // 8 bits
    const int b = blockIdx.x;

    // ---- 36 gate matrices. U = RZ(c)RY(b)RX(a); SU(2):
    // U = [[u00, -conj(u10)], [u10, conj(u00)]].
    if (t < NGATES) {
        const float* wp = weights + t * 3;
        float ha = 0.5f * wp[0], hb = 0.5f * wp[1], hc = 0.5f * wp[2];
        float ca = cosf(ha), sa = sinf(ha);
        float cb = cosf(hb), sb = sinf(hb);
        float ecr = cosf(hc), eci = -sinf(hc);   // e^{-i c/2}
        float t0 = cb * ca, t1 = sb * sa, t2 = sb * ca, t3 = cb * sa;
        float u00r =  ecr * t0 - eci * t1;
        float u00i =  ecr * t1 + eci * t0;
        float u10r =  ecr * t2 - eci * t3;
        float u10i = -ecr * t3 - eci * t2;
        Umat[t][0] = (v2f){ u00r,  u00i};   // u00
        Umat[t][1] = (v2f){-u10r,  u10i};   // u01 = -conj(u10)
        Umat[t][2] = (v2f){ u10r,  u10i};   // u10
        Umat[t][3] = (v2f){ u00r, -u00i};   // u11 = conj(u00)
    }

    // ---- Phase bases (f(i) = 18*(i>>4) + (i&15), v2f units).
    const int T  = t >> 4, u = t & 15;
    const int bA = 18 * T + u;                  // A write: i=(k<<8)|t, +288k
    const int bB = 288 * T + u;                 // B r/w:  i=(T<<8)|(k<<4)|u, +18k
    const int bC = 18 * t;                      // C r/w:  i=(t<<4)|k, +k (b128 pairs)
    const int tb  = t ^ (t >> 1);               // Gray(t), 8-bit
    const int tbx = tb ^ 128;
    const int pb0 = 18 * (tb  >> 4) + (tb  & 15);  // gather base, k even
    const int pb1 = 18 * (tbx >> 4) + (tbx & 15);  // gather base, k odd

    // ---- Measurement constants.
    float hw[N_WIRES];
    #pragma unroll
    for (int w = 0; w < N_WIRES; ++w) hw[w] = head_w[w];
    int it = t ^ (t >> 1); it ^= it >> 2; it ^= it >> 4;   // invGray8(t)
    float chi = 0.f;
    #pragma unroll
    for (int w = 0; w < 8; ++w)
        chi += ((it >> (7 - w)) & 1) ? -hw[w] : hw[w];
    const int parfill = (__popc(t) & 1) ? 0xF : 0;

    // ---- Initial load, A-layout: amp[k] = state[(k<<8)|t] (coalesced).
    v2f amp[PER];
    {
        const float* sp = state + (size_t)b * DIM;
        #pragma unroll
        for (int k = 0; k < PER; ++k)
            amp[k] = (v2f){sp[(k << 8) | t], 0.f};
    }
    __syncthreads();   // Umat ready

    #pragma unroll 1   // one copy of the circuit body (I-cache)
    for (int pass = 0; pass < 2; ++pass) {
        #pragma unroll
        for (int l = 0; l < 3; ++l) {
            const int gb = l * 12;
            if (l > 0) {
                // Gather through CNOT perm into A-layout:
                // new[(k<<8)|t] = old[j], j = (gray4(k)<<8)|(gray8(t)^((k&1)<<7)).
                const v2f* src = buf[(3 * l - 1) & 1];
                #pragma unroll
                for (int k = 0; k < PER; ++k) {
                    const int g = k ^ (k >> 1);             // gray4(k), static
                    amp[k] = src[((k & 1) ? pb1 : pb0) + 288 * g];
                }
            }

            // Group A: wires 0-3 (i bits 11-8 = k)
            apply4(amp, Umat, gb + 0);
            {
                v2f* w = &buf[(3 * l) & 1][bA];
                #pragma unroll
                for (int k = 0; k < PER; ++k) w[288 * k] = amp[k];
            }
            __syncthreads();
            {
                const v2f* r = &buf[(3 * l) & 1][bB];
                #pragma unroll
                for (int k = 0; k < PER; ++k) amp[k] = r[18 * k];
            }

            // Group B: wires 4-7 (i bits 7-4 = k)
            apply4(amp, Umat, gb + 4);
            {
                v2f* w = &buf[(3 * l + 1) & 1][bB];
                #pragma unroll
                for (int k = 0; k < PER; ++k) w[18 * k] = amp[k];
            }
            __syncthreads();
            {
                const float4* r = reinterpret_cast<const float4*>(&buf[(3 * l + 1) & 1][bC]);
                #pragma unroll
                for (int k = 0; k < PER / 2; ++k) {
                    float4 v = r[k];
                    amp[2 * k]     = (v2f){v.x, v.y};
                    amp[2 * k + 1] = (v2f){v.z, v.w};
                }
            }

            // Group C: wires 8-11 (i bits 3-0 = k)
            apply4(amp, Umat, gb + 8);
            if (l < 2) {
                float4* w = reinterpret_cast<float4*>(&buf[(3 * l + 2) & 1][bC]);
                #pragma unroll
                for (int k = 0; k < PER / 2; ++k)
                    w[k] = make_float4(amp[2 * k].x, amp[2 * k].y,
                                       amp[2 * k + 1].x, amp[2 * k + 1].y);
                __syncthreads();
            }
        }

        // ---- Measurement. Regs hold pre-perm state at j=(t<<4)|k; logical
        // m = invGray12(j): m[11:4]=invGray8(t), m[3:0]=invGray4(k)^(par(t)*0xF).
        float acc = 0.f;
        #pragma unroll
        for (int k = 0; k < PER; ++k) {
            int ml = (k ^ (k >> 1)); ml ^= ml >> 2; ml ^= parfill;  // m[3:0]
            float c = chi;
            c += ((ml >> 3) & 1) ? -hw[8]  : hw[8];
            c += ((ml >> 2) & 1) ? -hw[9]  : hw[9];
            c += ((ml >> 1) & 1) ? -hw[10] : hw[10];
            c += ( ml       & 1) ? -hw[11] : hw[11];
            float p = amp[k].x * amp[k].x + amp[k].y * amp[k].y;
            acc += p * c;
        }

        #pragma unroll
        for (int off = 32; off > 0; off >>= 1)
            acc += __shfl_down(acc, off, 64);
        if ((t & 63) == 0) redbuf[t >> 6] = acc;
        __syncthreads();
        if (t == 0) {
            float s = 0.f;
            #pragma unroll
            for (int q = 0; q < THREADS / 64; ++q) s += redbuf[q];
            s += head_b[0];
            if (pass == 0) out[b] = s;      // real result
            else           dbg[b] = s;      // diagnostic pass -> scratch
        }
        // pass 2 reuses final register state as input (unitary -> bounded).
        // Hazard: pass-2's first LDS write hits buf[0]; last pass-1 reads of
        // buf[0] (l=2 B-read) complete before the l=2 mid-phase barrier, and
        // the measurement barrier above orders redbuf. Safe.
    }
}

} // namespace

extern "C" void kernel_launch(void* const* d_in, const int* in_sizes, int n_in,
                              void* d_out, int out_size, void* d_ws, size_t ws_size,
                              hipStream_t stream)
{
    const float* state   = (const float*)d_in[0];  // (B, 4096) fp32
    const float* weights = (const float*)d_in[1];  // (3, 12, 3) fp32
    const float* head_w  = (const float*)d_in[2];  // (1, 12) fp32
    const float* head_b  = (const float*)d_in[3];  // (1,) fp32
    float* out = (float*)d_out;                    // (B,) fp32
    float* dbg = (float*)d_ws;                     // diagnostic-pass sink

    const int batch = in_sizes[0] / DIM;           // 512
    qcirc_kernel<<<batch, THREADS, 0, stream>>>(state, weights, head_w, head_b,
                                                out, dbg);
}

// Round 7
// 76.144 us; speedup vs baseline: 1.4050x; 1.2016x over previous
//
#include <hip/hip_runtime.h>

// Quantum circuit sim: 12 wires, DIM=4096, 3 layers, batch=512, fp32.
// R7 = R6 minus the diagnostic pass, plus occupancy push:
//  - single-pass (diagnostic double-pass removed; it was counter probing)
//  - SINGLE-buffered LDS (38 KB/block) + __launch_bounds__(256,4)
//    -> 4 blocks/CU, 4 waves/SIMD (R6 was 2; stall-bound per R5 counters).
//    Safe: B/C phases read & write identical per-thread addresses; the only
//    new hazard is gather-read vs A-write (one anti-dep barrier per layer).
//  - inline-asm v_pk_fma_f32/v_pk_mul_f32 complex core (R6): 8 VOP3P per
//    gate-pair, 2304 per thread total.
//  - LDS layout f(i) = 18*(i>>4)+(i&15): base VGPR + immediate offsets,
//    conflict-minimal every phase, C-phase 16-B aligned b128.
//  - CNOT chain folded to Gray map perm(i)=i^(i>>1) in gather addresses;
//    final perm folded into measurement weights via inverse-Gray.

namespace {

typedef float v2f __attribute__((ext_vector_type(2)));

constexpr int N_WIRES  = 12;
constexpr int DIM      = 1 << N_WIRES;        // 4096
constexpr int THREADS  = 256;
constexpr int PER      = 16;                  // amps per thread
constexpr int NGATES   = 36;
constexpr int PADC     = 4606;                // max f(i) = 288*15+18*15+15 = 4605

// ---- Packed complex helpers. v2f = (re, im) in a VGPR pair.
// d = u * p:
//   inst1: d.lo = p.re*u.re          d.hi = p.im*u.re
//   inst2: d.lo += p.im*(-u.im)      d.hi += p.re*u.im
__device__ __forceinline__ v2f cmul(v2f u, v2f p) {
    v2f d;
    asm("v_pk_mul_f32 %0, %1, %2 op_sel_hi:[1,0]"
        : "=v"(d) : "v"(p), "v"(u));
    asm("v_pk_fma_f32 %0, %1, %2, %0 op_sel:[1,1,0] op_sel_hi:[0,1,1] neg_lo:[0,1,0]"
        : "+v"(d) : "v"(p), "v"(u));
    return d;
}
// d += u * p
__device__ __forceinline__ void cfma(v2f& d, v2f u, v2f p) {
    asm("v_pk_fma_f32 %0, %1, %2, %0 op_sel_hi:[1,0,1]"
        : "+v"(d) : "v"(p), "v"(u));
    asm("v_pk_fma_f32 %0, %1, %2, %0 op_sel:[1,1,0] op_sel_hi:[0,1,1] neg_lo:[0,1,0]"
        : "+v"(d) : "v"(p), "v"(u));
}

// 4 in-register gates; gate gg pairs k-bit (3-gg). Um[g] = {u00,u01,u10,u11}.
__device__ __forceinline__ void apply4(v2f amp[PER], const v2f (*Um)[4], int gbase)
{
    #pragma unroll
    for (int gg = 0; gg < 4; ++gg) {
        const v2f u00 = Um[gbase + gg][0];
        const v2f u01 = Um[gbase + gg][1];
        const v2f u10 = Um[gbase + gg][2];
        const v2f u11 = Um[gbase + gg][3];
        const int st = 8 >> gg;
        #pragma unroll
        for (int k0 = 0; k0 < PER; ++k0) {
            if (k0 & st) continue;              // static under full unroll
            const int k1 = k0 | st;
            const v2f p = amp[k0], q = amp[k1];
            v2f np = cmul(u00, p); cfma(np, u01, q);
            v2f nq = cmul(u10, p); cfma(nq, u11, q);
            amp[k0] = np;
            amp[k1] = nq;
        }
    }
}

__global__ __launch_bounds__(THREADS, 4)
void qcirc_kernel(const float* __restrict__ state,
                  const float* __restrict__ weights,
                  const float* __restrict__ head_w,
                  const float* __restrict__ head_b,
                  float* __restrict__ out)
{
    __shared__ __align__(16) v2f buf[PADC];
    __shared__ __align__(16) v2f Umat[NGATES][4];
    __shared__ float redbuf[THREADS / 64];

    const int t = threadIdx.x;                 // 8 bits
    const int b = blockIdx.x;

    // ---- 36 gate matrices. U = RZ(c)RY(b)RX(a); SU(2):
    // U = [[u00, -conj(u10)], [u10, conj(u00)]].
    if (t < NGATES) {
        const float* wp = weights + t * 3;
        float ha = 0.5f * wp[0], hb = 0.5f * wp[1], hc = 0.5f * wp[2];
        float ca = cosf(ha), sa = sinf(ha);
        float cb = cosf(hb), sb = sinf(hb);
        float ecr = cosf(hc), eci = -sinf(hc);   // e^{-i c/2}
        float t0 = cb * ca, t1 = sb * sa, t2 = sb * ca, t3 = cb * sa;
        float u00r =  ecr * t0 - eci * t1;
        float u00i =  ecr * t1 + eci * t0;
        float u10r =  ecr * t2 - eci * t3;
        float u10i = -ecr * t3 - eci * t2;
        Umat[t][0] = (v2f){ u00r,  u00i};   // u00
        Umat[t][1] = (v2f){-u10r,  u10i};   // u01 = -conj(u10)
        Umat[t][2] = (v2f){ u10r,  u10i};   // u10
        Umat[t][3] = (v2f){ u00r, -u00i};   // u11 = conj(u00)
    }

    // ---- Phase bases (f(i) = 18*(i>>4) + (i&15), v2f units).
    const int T  = t >> 4, u = t & 15;
    const int bA = 18 * T + u;                  // A write: i=(k<<8)|t, +288k
    const int bB = 288 * T + u;                 // B r/w:  i=(T<<8)|(k<<4)|u, +18k
    const int bC = 18 * t;                      // C r/w:  i=(t<<4)|k, +k (b128 pairs)
    const int tb  = t ^ (t >> 1);               // Gray(t), 8-bit
    const int tbx = tb ^ 128;
    const int pb0 = 18 * (tb  >> 4) + (tb  & 15);  // gather base, k even
    const int pb1 = 18 * (tbx >> 4) + (tbx & 15);  // gather base, k odd

    // ---- Measurement constants.
    float hw[N_WIRES];
    #pragma unroll
    for (int w = 0; w < N_WIRES; ++w) hw[w] = head_w[w];
    int it = t ^ (t >> 1); it ^= it >> 2; it ^= it >> 4;   // invGray8(t)
    float chi = 0.f;
    #pragma unroll
    for (int w = 0; w < 8; ++w)
        chi += ((it >> (7 - w)) & 1) ? -hw[w] : hw[w];
    const int parfill = (__popc(t) & 1) ? 0xF : 0;

    // ---- Initial load, A-layout: amp[k] = state[(k<<8)|t] (coalesced).
    v2f amp[PER];
    {
        const float* sp = state + (size_t)b * DIM;
        #pragma unroll
        for (int k = 0; k < PER; ++k)
            amp[k] = (v2f){sp[(k << 8) | t], 0.f};
    }
    __syncthreads();   // Umat ready

    #pragma unroll
    for (int l = 0; l < 3; ++l) {
        const int gb = l * 12;
        if (l > 0) {
            // Gather through CNOT perm into A-layout:
            // new[(k<<8)|t] = old[j], j = (gray4(k)<<8)|(gray8(t)^((k&1)<<7)).
            #pragma unroll
            for (int k = 0; k < PER; ++k) {
                const int g = k ^ (k >> 1);             // gray4(k), static
                amp[k] = buf[((k & 1) ? pb1 : pb0) + 288 * g];
            }
            __syncthreads();   // anti-dep: all gather-reads before A-writes
        }

        // Group A: wires 0-3 (i bits 11-8 = k)
        apply4(amp, Umat, gb + 0);
        #pragma unroll
        for (int k = 0; k < PER; ++k) buf[bA + 288 * k] = amp[k];
        __syncthreads();

        // Group B: wires 4-7 (i bits 7-4 = k); read/write same per-thread addrs
        #pragma unroll
        for (int k = 0; k < PER; ++k) amp[k] = buf[bB + 18 * k];
        apply4(amp, Umat, gb + 4);
        #pragma unroll
        for (int k = 0; k < PER; ++k) buf[bB + 18 * k] = amp[k];
        __syncthreads();

        // Group C: wires 8-11 (i bits 3-0 = k); b128 pairs, same addrs
        {
            const float4* r = reinterpret_cast<const float4*>(&buf[bC]);
            #pragma unroll
            for (int k = 0; k < PER / 2; ++k) {
                float4 v = r[k];
                amp[2 * k]     = (v2f){v.x, v.y};
                amp[2 * k + 1] = (v2f){v.z, v.w};
            }
        }
        apply4(amp, Umat, gb + 8);
        if (l < 2) {
            float4* w = reinterpret_cast<float4*>(&buf[bC]);
            #pragma unroll
            for (int k = 0; k < PER / 2; ++k)
                w[k] = make_float4(amp[2 * k].x, amp[2 * k].y,
                                   amp[2 * k + 1].x, amp[2 * k + 1].y);
            __syncthreads();   // C-writes visible to next layer's gather
        }
    }

    // ---- Measurement. Regs hold pre-perm state at j=(t<<4)|k; logical
    // m = invGray12(j): m[11:4]=invGray8(t), m[3:0]=invGray4(k)^(par(t)*0xF).
    float acc = 0.f;
    #pragma unroll
    for (int k = 0; k < PER; ++k) {
        int ml = (k ^ (k >> 1)); ml ^= ml >> 2; ml ^= parfill;  // m[3:0]
        float c = chi;
        c += ((ml >> 3) & 1) ? -hw[8]  : hw[8];
        c += ((ml >> 2) & 1) ? -hw[9]  : hw[9];
        c += ((ml >> 1) & 1) ? -hw[10] : hw[10];
        c += ( ml       & 1) ? -hw[11] : hw[11];
        float p = amp[k].x * amp[k].x + amp[k].y * amp[k].y;
        acc += p * c;
    }

    #pragma unroll
    for (int off = 32; off > 0; off >>= 1)
        acc += __shfl_down(acc, off, 64);
    if ((t & 63) == 0) redbuf[t >> 6] = acc;
    __syncthreads();
    if (t == 0) {
        float s = 0.f;
        #pragma unroll
        for (int q = 0; q < THREADS / 64; ++q) s += redbuf[q];
        out[b] = s + head_b[0];
    }
}

} // namespace

extern "C" void kernel_launch(void* const* d_in, const int* in_sizes, int n_in,
                              void* d_out, int out_size, void* d_ws, size_t ws_size,
                              hipStream_t stream)
{
    const float* state   = (const float*)d_in[0];  // (B, 4096) fp32
    const float* weights = (const float*)d_in[1];  // (3, 12, 3) fp32
    const float* head_w  = (const float*)d_in[2];  // (1, 12) fp32
    const float* head_b  = (const float*)d_in[3];  // (1,) fp32
    float* out = (float*)d_out;                    // (B,) fp32

    const int batch = in_sizes[0] / DIM;           // 512
    qcirc_kernel<<<batch, THREADS, 0, stream>>>(state, weights, head_w, head_b, out);
}